// Round 1
// baseline (3015.609 us; speedup 1.0000x reference)
//
#include <hip/hip_runtime.h>
#include <cstdint>
#include <cstddef>

typedef _Float16 f16;
typedef _Float16 f16x8 __attribute__((ext_vector_type(8)));
typedef float f32x4 __attribute__((ext_vector_type(4)));

#define MFMA16(a,b,c) __builtin_amdgcn_mfma_f32_16x16x32_f16((a),(b),(c),0,0,0)

constexpr int Bb = 64, Tt = 48, Ee = 620, Hh = 2400;
constexpr int G3 = 3*Hh;        // 7200
constexpr int EPAD = 640;       // 620 padded to mult of 32
constexpr int JT = Hh/16;       // 150 j-tiles
constexpr int KK_HH = Hh/32;    // 75
constexpr int KK_IH = EPAD/32;  // 20
constexpr int NT_ALL = G3/16;   // 450

constexpr size_t WHH_ELEMS = (size_t)NT_ALL*KK_HH*64*8;  // 17,280,000
constexpr size_t WIH_ELEMS = (size_t)NT_ALL*KK_IH*64*8;  // 4,608,000
constexpr size_t X_ELEMS   = (size_t)Bb*Tt*EPAD;         // 1,966,080
constexpr size_t GI_ELEMS  = (size_t)Bb*Tt*G3;           // 22,118,400
constexpr size_t HB        = (size_t)Bb*Hh;              // 153,600

constexpr float F16_MIN_NORMAL = 6.103515625e-05f;
constexpr float LO_SCALE = 2048.0f;
constexpr float LO_INV   = 1.0f/2048.0f;

__device__ __forceinline__ float sigf(float x){ return 1.0f/(1.0f+expf(-x)); }

// ---- pack w_hh into MFMA B-fragment layout, split hi/lo(scaled 2^11) fp16 ----
// elem (nt,kk,l,j) at idx ((nt*KK+kk)*64+l)*8+j  holds  W[nt*16+(l&15)][kk*32+((l>>4)<<3)+j]
__global__ __launch_bounds__(256) void k_pack_whh(const float* __restrict__ w,
                                                  f16* __restrict__ hi, f16* __restrict__ lo){
    size_t idx = (size_t)blockIdx.x*256 + threadIdx.x;
    if (idx >= WHH_ELEMS) return;
    int j = (int)(idx & 7);
    int l = (int)((idx >> 3) & 63);
    size_t rem = idx >> 9;
    int kk = (int)(rem % KK_HH);
    int nt = (int)(rem / KK_HH);
    int row = nt*16 + (l & 15);
    int k   = kk*32 + ((l >> 4) << 3) + j;
    float v = w[(size_t)row*Hh + k];
    f16 h = (fabsf(v) >= F16_MIN_NORMAL) ? (f16)v : (f16)0.0f;
    hi[idx] = h;
    lo[idx] = (f16)((v - (float)h) * LO_SCALE);
}

__global__ __launch_bounds__(256) void k_pack_wih(const float* __restrict__ w, f16* __restrict__ p){
    size_t idx = (size_t)blockIdx.x*256 + threadIdx.x;
    if (idx >= WIH_ELEMS) return;
    int j = (int)(idx & 7);
    int l = (int)((idx >> 3) & 63);
    size_t rem = idx >> 9;
    int kk = (int)(rem % KK_IH);
    int nt = (int)(rem / KK_IH);
    int row = nt*16 + (l & 15);
    int k   = kk*32 + ((l >> 4) << 3) + j;
    float v = (k < Ee) ? w[(size_t)row*Ee + k] : 0.0f;
    p[idx] = (f16)v;
}

// ---- gather embeddings into fp16 [3072][640] (tail zero-padded) ----
__global__ __launch_bounds__(256) void k_gather_x(const int* __restrict__ tokens,
                                                  const float* __restrict__ emb,
                                                  f16* __restrict__ x){
    size_t idx = (size_t)blockIdx.x*256 + threadIdx.x;
    if (idx >= X_ELEMS) return;
    int row = (int)(idx / EPAD);
    int e   = (int)(idx % EPAD);
    int tok = tokens[row];
    float v = (e < Ee) ? emb[(size_t)tok*Ee + e] : 0.0f;
    x[idx] = (f16)v;
}

// ---- gi = x @ w_ih^T  (fp16 MFMA, fp32 accum), output fp16 [t][b][7200] ----
__global__ __launch_bounds__(256) void k_gi_gemm(const f16* __restrict__ x,
                                                 const f16* __restrict__ wp,
                                                 f16* __restrict__ gi){
    const int w = threadIdx.x >> 6;
    const int l = threadIdx.x & 63;
    const int m0  = blockIdx.x*64 + w*16;
    const int nt0 = blockIdx.y*3;

    f32x4 z4 = {0.f,0.f,0.f,0.f};
    f32x4 a0 = z4, a1 = z4, a2 = z4;

    const f16x8* pa  = (const f16x8*)(x + (size_t)(m0 + (l & 15))*EPAD + ((l >> 4) << 3));
    const f16x8* pb0 = (const f16x8*)(wp + ((size_t)((nt0+0)*KK_IH)*64 + l)*8);
    const f16x8* pb1 = (const f16x8*)(wp + ((size_t)((nt0+1)*KK_IH)*64 + l)*8);
    const f16x8* pb2 = (const f16x8*)(wp + ((size_t)((nt0+2)*KK_IH)*64 + l)*8);

    for (int kk=0; kk<KK_IH; ++kk){
        f16x8 a = pa[(size_t)kk*4];
        a0 = MFMA16(a, pb0[(size_t)kk*64], a0);
        a1 = MFMA16(a, pb1[(size_t)kk*64], a1);
        a2 = MFMA16(a, pb2[(size_t)kk*64], a2);
    }
    const int rb = (l >> 4)*4;
    #pragma unroll
    for (int r=0; r<4; ++r){
        int m = m0 + rb + r;
        int b = m / Tt, t = m % Tt;
        size_t base = ((size_t)t*Bb + b)*G3;
        int n0 = nt0*16 + (l & 15);
        gi[base + n0     ] = (f16)a0[r];
        gi[base + n0 + 16] = (f16)a1[r];
        gi[base + n0 + 32] = (f16)a2[r];
    }
}

// ---- one GRU timestep: gh (split-precision MFMA) + fused gates + out select ----
__global__ __launch_bounds__(256) void k_gru_step(
    int t,
    const f16* __restrict__ hhi, const f16* __restrict__ hlo, const float* __restrict__ h32,
    f16* __restrict__ nhhi, f16* __restrict__ nhlo, float* __restrict__ nh32,
    const f16* __restrict__ whi, const f16* __restrict__ wlo,
    const f16* __restrict__ gi, const float* __restrict__ bhh,
    const int* __restrict__ lens, float* __restrict__ out)
{
    const int w  = threadIdx.x >> 6;   // wave = M-tile (16 batch rows)
    const int l  = threadIdx.x & 63;
    const int jt = blockIdx.x;         // 0..149

    f32x4 z4 = {0.f,0.f,0.f,0.f};
    f32x4 ah0=z4, ah1=z4, ah2=z4;      // hi*hi accumulators (r,z,n)
    f32x4 al0=z4, al1=z4, al2=z4;      // scaled-lo accumulators

    const size_t aoff = (size_t)(w*16 + (l & 15))*Hh + ((l >> 4) << 3);
    const f16x8* pah = (const f16x8*)(hhi + aoff);
    const f16x8* pal = (const f16x8*)(hlo + aoff);
    const size_t bo0 = ((size_t)((0*JT + jt)*KK_HH)*64 + l)*8;
    const size_t bo1 = ((size_t)((1*JT + jt)*KK_HH)*64 + l)*8;
    const size_t bo2 = ((size_t)((2*JT + jt)*KK_HH)*64 + l)*8;
    const f16x8* pb0h = (const f16x8*)(whi + bo0);
    const f16x8* pb1h = (const f16x8*)(whi + bo1);
    const f16x8* pb2h = (const f16x8*)(whi + bo2);
    const f16x8* pb0l = (const f16x8*)(wlo + bo0);
    const f16x8* pb1l = (const f16x8*)(wlo + bo1);
    const f16x8* pb2l = (const f16x8*)(wlo + bo2);

    for (int kk=0; kk<KK_HH; ++kk){
        f16x8 ahi = pah[(size_t)kk*4];
        f16x8 alo = pal[(size_t)kk*4];
        f16x8 b0h = pb0h[(size_t)kk*64], b0l = pb0l[(size_t)kk*64];
        ah0 = MFMA16(ahi, b0h, ah0);
        al0 = MFMA16(alo, b0h, al0);
        al0 = MFMA16(ahi, b0l, al0);
        f16x8 b1h = pb1h[(size_t)kk*64], b1l = pb1l[(size_t)kk*64];
        ah1 = MFMA16(ahi, b1h, ah1);
        al1 = MFMA16(alo, b1h, al1);
        al1 = MFMA16(ahi, b1l, al1);
        f16x8 b2h = pb2h[(size_t)kk*64], b2l = pb2l[(size_t)kk*64];
        ah2 = MFMA16(ahi, b2h, ah2);
        al2 = MFMA16(alo, b2h, al2);
        al2 = MFMA16(ahi, b2l, al2);
    }

    const int j = jt*16 + (l & 15);
    const float br = bhh[j], bz = bhh[Hh + j], bn = bhh[2*Hh + j];
    const f16* git = gi + (size_t)t*Bb*G3;
    const int rbase = (l >> 4)*4;
    #pragma unroll
    for (int r=0; r<4; ++r){
        const int b = w*16 + rbase + r;
        float ghr = ah0[r] + al0[r]*LO_INV + br;
        float ghz = ah1[r] + al1[r]*LO_INV + bz;
        float ghn = ah2[r] + al2[r]*LO_INV + bn;
        float gir = (float)git[(size_t)b*G3 + j];
        float giz = (float)git[(size_t)b*G3 + Hh + j];
        float gin = (float)git[(size_t)b*G3 + 2*Hh + j];
        float rg = sigf(gir + ghr);
        float zg = sigf(giz + ghz);
        float ng = tanhf(gin + rg*ghn);
        float hp = h32[(size_t)b*Hh + j];
        float hn = (1.0f - zg)*ng + zg*hp;
        nh32[(size_t)b*Hh + j] = hn;
        f16 hi16 = (fabsf(hn) >= F16_MIN_NORMAL) ? (f16)hn : (f16)0.0f;
        nhhi[(size_t)b*Hh + j] = hi16;
        nhlo[(size_t)b*Hh + j] = (f16)((hn - (float)hi16)*LO_SCALE);
        if (lens[b] - 1 == t) out[(size_t)b*Hh + j] = hn;
    }
}

// ---- fallback (small ws): plain fp32, LDS-tiled, on-the-fly gi ----
__global__ __launch_bounds__(256) void k_fb_step(
    int t, const float* __restrict__ hcur, float* __restrict__ hnext,
    const int* __restrict__ tokens, const int* __restrict__ lens,
    const float* __restrict__ emb, const float* __restrict__ wih,
    const float* __restrict__ whh, const float* __restrict__ bhh,
    float* __restrict__ out)
{
    __shared__ float sbuf[64][17];
    __shared__ int stok[64];
    const int tid = threadIdx.x;
    const int jl = tid & 7, rl = tid >> 3;
    const int j = blockIdx.x*8 + jl;
    if (tid < 64) stok[tid] = tokens[tid*Tt + t];

    float accr[2]={0.f,0.f}, accz[2]={0.f,0.f}, accnh[2]={0.f,0.f}, accni[2]={0.f,0.f};

    for (int k0=0; k0<Hh; k0+=16){
        __syncthreads();
        for (int e=tid; e<1024; e+=256)
            sbuf[e>>4][e&15] = hcur[(size_t)(e>>4)*Hh + k0 + (e&15)];
        __syncthreads();
        for (int kk=0; kk<16; ++kk){
            int k = k0 + kk;
            float wr = whh[(size_t)j*Hh + k];
            float wz = whh[(size_t)(Hh + j)*Hh + k];
            float wn = whh[(size_t)(2*Hh + j)*Hh + k];
            #pragma unroll
            for (int rr=0; rr<2; ++rr){
                float hv = sbuf[rl*2 + rr][kk];
                accr[rr] += wr*hv; accz[rr] += wz*hv; accnh[rr] += wn*hv;
            }
        }
    }
    for (int k0=0; k0<Ee; k0+=16){
        int lim = (Ee - k0 < 16) ? (Ee - k0) : 16;
        __syncthreads();
        for (int e=tid; e<1024; e+=256){
            int rr = e>>4, kkk = e&15;
            sbuf[rr][kkk] = (kkk < lim) ? emb[(size_t)stok[rr]*Ee + k0 + kkk] : 0.0f;
        }
        __syncthreads();
        for (int kk=0; kk<lim; ++kk){
            int k = k0 + kk;
            float wr = wih[(size_t)j*Ee + k];
            float wz = wih[(size_t)(Hh + j)*Ee + k];
            float wn = wih[(size_t)(2*Hh + j)*Ee + k];
            #pragma unroll
            for (int rr=0; rr<2; ++rr){
                float hv = sbuf[rl*2 + rr][kk];
                accr[rr] += wr*hv; accz[rr] += wz*hv; accni[rr] += wn*hv;
            }
        }
    }
    const float br = bhh[j], bz = bhh[Hh + j], bn = bhh[2*Hh + j];
    #pragma unroll
    for (int rr=0; rr<2; ++rr){
        int b = rl*2 + rr;
        float rg = sigf(accr[rr] + br);
        float zg = sigf(accz[rr] + bz);
        float ng = tanhf(accni[rr] + rg*(accnh[rr] + bn));
        float hp = hcur[(size_t)b*Hh + j];
        float hn = (1.0f - zg)*ng + zg*hp;
        hnext[(size_t)b*Hh + j] = hn;
        if (lens[b] - 1 == t) out[(size_t)b*Hh + j] = hn;
    }
}

extern "C" void kernel_launch(void* const* d_in, const int* in_sizes, int n_in,
                              void* d_out, int out_size, void* d_ws, size_t ws_size,
                              hipStream_t stream)
{
    const int*   tokens = (const int*)d_in[0];
    const int*   lens   = (const int*)d_in[1];
    const float* emb    = (const float*)d_in[2];
    const float* wih    = (const float*)d_in[3];
    const float* whh    = (const float*)d_in[4];
    const float* bhh    = (const float*)d_in[5];
    float* out = (float*)d_out;

    char* ws = (char*)d_ws;
    const size_t o_whi = 0;
    const size_t o_wlo = o_whi + WHH_ELEMS*2;
    const size_t o_wih = o_wlo + WHH_ELEMS*2;
    const size_t o_x   = o_wih + WIH_ELEMS*2;
    const size_t o_gi  = o_x   + X_ELEMS*2;
    const size_t o_h16 = o_gi  + GI_ELEMS*2;
    const size_t o_h32 = o_h16 + 4*HB*2;
    const size_t need  = o_h32 + 2*HB*4;   // ~129 MB

    if (ws_size >= need) {
        f16* whip = (f16*)(ws + o_whi);
        f16* wlop = (f16*)(ws + o_wlo);
        f16* wihp = (f16*)(ws + o_wih);
        f16* xp   = (f16*)(ws + o_x);
        f16* gip  = (f16*)(ws + o_gi);
        f16* h16  = (f16*)(ws + o_h16);
        float* h32 = (float*)(ws + o_h32);
        f16* hhi[2]    = { h16,          h16 + 2*HB };
        f16* hlo[2]    = { h16 + HB,     h16 + 3*HB };
        float* h32b[2] = { h32, h32 + HB };

        hipMemsetAsync(ws + o_h16, 0, 4*HB*2 + 2*HB*4, stream);
        k_pack_whh<<<dim3(67500), dim3(256), 0, stream>>>(whh, whip, wlop);
        k_pack_wih<<<dim3(18000), dim3(256), 0, stream>>>(wih, wihp);
        k_gather_x<<<dim3(7680),  dim3(256), 0, stream>>>(tokens, emb, xp);
        k_gi_gemm<<<dim3(48,150), dim3(256), 0, stream>>>(xp, wihp, gip);
        for (int t=0; t<Tt; ++t){
            int c = t & 1, n = c ^ 1;
            k_gru_step<<<dim3(JT), dim3(256), 0, stream>>>(t,
                hhi[c], hlo[c], h32b[c], hhi[n], hlo[n], h32b[n],
                whip, wlop, gip, bhh, lens, out);
        }
    } else {
        float* h32 = (float*)ws;
        float* hb[2] = { h32, h32 + HB };
        hipMemsetAsync(ws, 0, 2*HB*4, stream);
        for (int t=0; t<Tt; ++t){
            int c = t & 1, n = c ^ 1;
            k_fb_step<<<dim3(300), dim3(256), 0, stream>>>(t, hb[c], hb[n],
                tokens, lens, emb, wih, whh, bhh, out);
        }
    }
}

// Round 2
// 1470.302 us; speedup vs baseline: 2.0510x; 2.0510x over previous
//
#include <hip/hip_runtime.h>
#include <cstdint>
#include <cstddef>

typedef _Float16 f16;
typedef _Float16 f16x8 __attribute__((ext_vector_type(8)));
typedef float f32x4 __attribute__((ext_vector_type(4)));

#define MFMA16(a,b,c) __builtin_amdgcn_mfma_f32_16x16x32_f16((a),(b),(c),0,0,0)

constexpr int Bb = 64, Tt = 48, Ee = 620, Hh = 2400;
constexpr int G3 = 3*Hh;        // 7200
constexpr int EPAD = 640;       // 620 padded to mult of 32
constexpr int JT = Hh/16;       // 150 j-tiles
constexpr int KK_HH = Hh/32;    // 75
constexpr int KK_IH = EPAD/32;  // 20
constexpr int NT_ALL = G3/16;   // 450
constexpr int KS = 5;           // K-split factor for recurrence GEMM
constexpr int KKB = KK_HH/KS;   // 15 kk-iterations per block

constexpr size_t WHH_ELEMS = (size_t)NT_ALL*KK_HH*64*8;  // 17,280,000
constexpr size_t WIH_ELEMS = (size_t)NT_ALL*KK_IH*64*8;  // 4,608,000
constexpr size_t X_ELEMS   = (size_t)Bb*Tt*EPAD;         // 1,966,080
constexpr size_t GI_ELEMS  = (size_t)Bb*Tt*G3;           // 22,118,400
constexpr size_t HB        = (size_t)Bb*Hh;              // 153,600
constexpr size_t PART_ELEMS = (size_t)3*KS*HB;           // 2,304,000 f32 = 9,216,000 B

constexpr float F16_MIN_NORMAL = 6.103515625e-05f;
constexpr float LO_SCALE = 2048.0f;
constexpr float LO_INV   = 1.0f/2048.0f;

__device__ __forceinline__ float sigf(float x){ return 1.0f/(1.0f+expf(-x)); }

// ---- pack w_hh into MFMA B-fragment layout, split hi/lo(scaled 2^11) fp16 ----
// elem (nt,kk,l,j) at idx ((nt*KK+kk)*64+l)*8+j  holds  W[nt*16+(l&15)][kk*32+((l>>4)<<3)+j]
__global__ __launch_bounds__(256) void k_pack_whh(const float* __restrict__ w,
                                                  f16* __restrict__ hi, f16* __restrict__ lo){
    size_t idx = (size_t)blockIdx.x*256 + threadIdx.x;
    if (idx >= WHH_ELEMS) return;
    int j = (int)(idx & 7);
    int l = (int)((idx >> 3) & 63);
    size_t rem = idx >> 9;
    int kk = (int)(rem % KK_HH);
    int nt = (int)(rem / KK_HH);
    int row = nt*16 + (l & 15);
    int k   = kk*32 + ((l >> 4) << 3) + j;
    float v = w[(size_t)row*Hh + k];
    f16 h = (fabsf(v) >= F16_MIN_NORMAL) ? (f16)v : (f16)0.0f;
    hi[idx] = h;
    lo[idx] = (f16)((v - (float)h) * LO_SCALE);
}

__global__ __launch_bounds__(256) void k_pack_wih(const float* __restrict__ w, f16* __restrict__ p){
    size_t idx = (size_t)blockIdx.x*256 + threadIdx.x;
    if (idx >= WIH_ELEMS) return;
    int j = (int)(idx & 7);
    int l = (int)((idx >> 3) & 63);
    size_t rem = idx >> 9;
    int kk = (int)(rem % KK_IH);
    int nt = (int)(rem / KK_IH);
    int row = nt*16 + (l & 15);
    int k   = kk*32 + ((l >> 4) << 3) + j;
    float v = (k < Ee) ? w[(size_t)row*Ee + k] : 0.0f;
    p[idx] = (f16)v;
}

// ---- gather embeddings into fp16 [3072][640] (tail zero-padded) ----
__global__ __launch_bounds__(256) void k_gather_x(const int* __restrict__ tokens,
                                                  const float* __restrict__ emb,
                                                  f16* __restrict__ x){
    size_t idx = (size_t)blockIdx.x*256 + threadIdx.x;
    if (idx >= X_ELEMS) return;
    int row = (int)(idx / EPAD);
    int e   = (int)(idx % EPAD);
    int tok = tokens[row];
    float v = (e < Ee) ? emb[(size_t)tok*Ee + e] : 0.0f;
    x[idx] = (f16)v;
}

// ---- gi = x @ w_ih^T  (fp16 MFMA, fp32 accum), output fp16 [t][b][7200] ----
// depth-1 software pipeline: issue kk+1's loads before kk's MFMAs
__global__ __launch_bounds__(256) void k_gi_gemm(const f16* __restrict__ x,
                                                 const f16* __restrict__ wp,
                                                 f16* __restrict__ gi){
    const int w = threadIdx.x >> 6;
    const int l = threadIdx.x & 63;
    const int m0  = blockIdx.x*64 + w*16;
    const int nt0 = blockIdx.y*3;

    f32x4 z4 = {0.f,0.f,0.f,0.f};
    f32x4 a0 = z4, a1 = z4, a2 = z4;

    const f16x8* pa  = (const f16x8*)(x + (size_t)(m0 + (l & 15))*EPAD + ((l >> 4) << 3));
    const f16x8* pb0 = (const f16x8*)(wp + ((size_t)((nt0+0)*KK_IH)*64 + l)*8);
    const f16x8* pb1 = (const f16x8*)(wp + ((size_t)((nt0+1)*KK_IH)*64 + l)*8);
    const f16x8* pb2 = (const f16x8*)(wp + ((size_t)((nt0+2)*KK_IH)*64 + l)*8);

    f16x8 ca = pa[0], cb0 = pb0[0], cb1 = pb1[0], cb2 = pb2[0];
    #pragma unroll
    for (int kk=0; kk<KK_IH; ++kk){
        f16x8 na, nb0, nb1, nb2;
        if (kk+1 < KK_IH){
            na  = pa [(size_t)(kk+1)*4];
            nb0 = pb0[(size_t)(kk+1)*64];
            nb1 = pb1[(size_t)(kk+1)*64];
            nb2 = pb2[(size_t)(kk+1)*64];
        }
        a0 = MFMA16(ca, cb0, a0);
        a1 = MFMA16(ca, cb1, a1);
        a2 = MFMA16(ca, cb2, a2);
        if (kk+1 < KK_IH){ ca = na; cb0 = nb0; cb1 = nb1; cb2 = nb2; }
    }
    const int rb = (l >> 4)*4;
    #pragma unroll
    for (int r=0; r<4; ++r){
        int m = m0 + rb + r;
        int b = m / Tt, t = m % Tt;
        size_t base = ((size_t)t*Bb + b)*G3;
        int n0 = nt0*16 + (l & 15);
        gi[base + n0     ] = (f16)a0[r];
        gi[base + n0 + 16] = (f16)a1[r];
        gi[base + n0 + 32] = (f16)a2[r];
    }
}

// ---- recurrence GEMM, K-split: partial gh sums for one (jt, ks) ----
__global__ __launch_bounds__(256) void k_gru_mfma(
    const f16* __restrict__ hhi, const f16* __restrict__ hlo,
    const f16* __restrict__ whi, const f16* __restrict__ wlo,
    float* __restrict__ part)
{
    const int w  = threadIdx.x >> 6;   // wave = M-tile (16 batch rows)
    const int l  = threadIdx.x & 63;
    const int jt = blockIdx.x;         // 0..149
    const int ks = blockIdx.y;         // 0..4

    f32x4 z4 = {0.f,0.f,0.f,0.f};
    f32x4 ah0=z4, ah1=z4, ah2=z4;      // hi*hi accumulators (r,z,n)
    f32x4 al0=z4, al1=z4, al2=z4;      // scaled-lo accumulators

    const size_t aoff = (size_t)(w*16 + (l & 15))*Hh + (size_t)ks*(KKB*32) + ((l >> 4) << 3);
    const f16x8* pah = (const f16x8*)(hhi + aoff);
    const f16x8* pal = (const f16x8*)(hlo + aoff);
    const size_t kb = (size_t)ks*KKB;
    const f16x8* pb0h = (const f16x8*)(whi + (((size_t)(0*JT+jt)*KK_HH + kb)*64 + l)*8);
    const f16x8* pb1h = (const f16x8*)(whi + (((size_t)(1*JT+jt)*KK_HH + kb)*64 + l)*8);
    const f16x8* pb2h = (const f16x8*)(whi + (((size_t)(2*JT+jt)*KK_HH + kb)*64 + l)*8);
    const f16x8* pb0l = (const f16x8*)(wlo + (((size_t)(0*JT+jt)*KK_HH + kb)*64 + l)*8);
    const f16x8* pb1l = (const f16x8*)(wlo + (((size_t)(1*JT+jt)*KK_HH + kb)*64 + l)*8);
    const f16x8* pb2l = (const f16x8*)(wlo + (((size_t)(2*JT+jt)*KK_HH + kb)*64 + l)*8);

    f16x8 cah = pah[0], cal = pal[0];
    f16x8 cb0h = pb0h[0], cb1h = pb1h[0], cb2h = pb2h[0];
    f16x8 cb0l = pb0l[0], cb1l = pb1l[0], cb2l = pb2l[0];

    #pragma unroll
    for (int kk=0; kk<KKB; ++kk){
        f16x8 nah, nal, nb0h, nb1h, nb2h, nb0l, nb1l, nb2l;
        if (kk+1 < KKB){
            nb0h = pb0h[(size_t)(kk+1)*64];
            nb1h = pb1h[(size_t)(kk+1)*64];
            nb2h = pb2h[(size_t)(kk+1)*64];
            nb0l = pb0l[(size_t)(kk+1)*64];
            nb1l = pb1l[(size_t)(kk+1)*64];
            nb2l = pb2l[(size_t)(kk+1)*64];
            nah  = pah [(size_t)(kk+1)*4];
            nal  = pal [(size_t)(kk+1)*4];
        }
        ah0 = MFMA16(cah, cb0h, ah0);
        al0 = MFMA16(cal, cb0h, al0);
        al0 = MFMA16(cah, cb0l, al0);
        ah1 = MFMA16(cah, cb1h, ah1);
        al1 = MFMA16(cal, cb1h, al1);
        al1 = MFMA16(cah, cb1l, al1);
        ah2 = MFMA16(cah, cb2h, ah2);
        al2 = MFMA16(cal, cb2h, al2);
        al2 = MFMA16(cah, cb2l, al2);
        if (kk+1 < KKB){
            cah=nah; cal=nal;
            cb0h=nb0h; cb1h=nb1h; cb2h=nb2h;
            cb0l=nb0l; cb1l=nb1l; cb2l=nb2l;
        }
    }

    const int j = jt*16 + (l & 15);
    const int rbase = (l >> 4)*4;
    #pragma unroll
    for (int r=0; r<4; ++r){
        const int b = w*16 + rbase + r;
        part[((size_t)(0*KS+ks)*Bb + b)*Hh + j] = ah0[r] + al0[r]*LO_INV;
        part[((size_t)(1*KS+ks)*Bb + b)*Hh + j] = ah1[r] + al1[r]*LO_INV;
        part[((size_t)(2*KS+ks)*Bb + b)*Hh + j] = ah2[r] + al2[r]*LO_INV;
    }
}

// ---- sum K-split partials + gates + h update + length-select output ----
__global__ __launch_bounds__(256) void k_combine(
    int t, const float* __restrict__ part, const f16* __restrict__ gi,
    const float* __restrict__ h32, float* __restrict__ nh32,
    f16* __restrict__ nhhi, f16* __restrict__ nhlo,
    const float* __restrict__ bhh, const int* __restrict__ lens,
    float* __restrict__ out)
{
    const int idx = blockIdx.x*256 + threadIdx.x;   // 0 .. 153599
    const int b = idx / Hh, j = idx - b*Hh;
    float sr = 0.f, sz = 0.f, sn = 0.f;
    #pragma unroll
    for (int ks=0; ks<KS; ++ks){
        sr += part[((size_t)(0*KS+ks)*Bb + b)*Hh + j];
        sz += part[((size_t)(1*KS+ks)*Bb + b)*Hh + j];
        sn += part[((size_t)(2*KS+ks)*Bb + b)*Hh + j];
    }
    const f16* git = gi + ((size_t)t*Bb + b)*G3;
    float rg = sigf((float)git[j]        + sr + bhh[j]);
    float zg = sigf((float)git[Hh + j]   + sz + bhh[Hh + j]);
    float ng = tanhf((float)git[2*Hh + j] + rg*(sn + bhh[2*Hh + j]));
    float hp = h32[idx];
    float hn = (1.0f - zg)*ng + zg*hp;
    nh32[idx] = hn;
    f16 hi16 = (fabsf(hn) >= F16_MIN_NORMAL) ? (f16)hn : (f16)0.0f;
    nhhi[idx] = hi16;
    nhlo[idx] = (f16)((hn - (float)hi16)*LO_SCALE);
    if (lens[b] - 1 == t) out[idx] = hn;
}

// ---- fallback (small ws): plain fp32, LDS-tiled, on-the-fly gi ----
__global__ __launch_bounds__(256) void k_fb_step(
    int t, const float* __restrict__ hcur, float* __restrict__ hnext,
    const int* __restrict__ tokens, const int* __restrict__ lens,
    const float* __restrict__ emb, const float* __restrict__ wih,
    const float* __restrict__ whh, const float* __restrict__ bhh,
    float* __restrict__ out)
{
    __shared__ float sbuf[64][17];
    __shared__ int stok[64];
    const int tid = threadIdx.x;
    const int jl = tid & 7, rl = tid >> 3;
    const int j = blockIdx.x*8 + jl;
    if (tid < 64) stok[tid] = tokens[tid*Tt + t];

    float accr[2]={0.f,0.f}, accz[2]={0.f,0.f}, accnh[2]={0.f,0.f}, accni[2]={0.f,0.f};

    for (int k0=0; k0<Hh; k0+=16){
        __syncthreads();
        for (int e=tid; e<1024; e+=256)
            sbuf[e>>4][e&15] = hcur[(size_t)(e>>4)*Hh + k0 + (e&15)];
        __syncthreads();
        for (int kk=0; kk<16; ++kk){
            int k = k0 + kk;
            float wr = whh[(size_t)j*Hh + k];
            float wz = whh[(size_t)(Hh + j)*Hh + k];
            float wn = whh[(size_t)(2*Hh + j)*Hh + k];
            #pragma unroll
            for (int rr=0; rr<2; ++rr){
                float hv = sbuf[rl*2 + rr][kk];
                accr[rr] += wr*hv; accz[rr] += wz*hv; accnh[rr] += wn*hv;
            }
        }
    }
    for (int k0=0; k0<Ee; k0+=16){
        int lim = (Ee - k0 < 16) ? (Ee - k0) : 16;
        __syncthreads();
        for (int e=tid; e<1024; e+=256){
            int rr = e>>4, kkk = e&15;
            sbuf[rr][kkk] = (kkk < lim) ? emb[(size_t)stok[rr]*Ee + k0 + kkk] : 0.0f;
        }
        __syncthreads();
        for (int kk=0; kk<lim; ++kk){
            int k = k0 + kk;
            float wr = wih[(size_t)j*Ee + k];
            float wz = wih[(size_t)(Hh + j)*Ee + k];
            float wn = wih[(size_t)(2*Hh + j)*Ee + k];
            #pragma unroll
            for (int rr=0; rr<2; ++rr){
                float hv = sbuf[rl*2 + rr][kk];
                accr[rr] += wr*hv; accz[rr] += wz*hv; accni[rr] += wn*hv;
            }
        }
    }
    const float br = bhh[j], bz = bhh[Hh + j], bn = bhh[2*Hh + j];
    #pragma unroll
    for (int rr=0; rr<2; ++rr){
        int b = rl*2 + rr;
        float rg = sigf(accr[rr] + br);
        float zg = sigf(accz[rr] + bz);
        float ng = tanhf(accni[rr] + rg*(accnh[rr] + bn));
        float hp = hcur[(size_t)b*Hh + j];
        float hn = (1.0f - zg)*ng + zg*hp;
        hnext[(size_t)b*Hh + j] = hn;
        if (lens[b] - 1 == t) out[(size_t)b*Hh + j] = hn;
    }
}

extern "C" void kernel_launch(void* const* d_in, const int* in_sizes, int n_in,
                              void* d_out, int out_size, void* d_ws, size_t ws_size,
                              hipStream_t stream)
{
    const int*   tokens = (const int*)d_in[0];
    const int*   lens   = (const int*)d_in[1];
    const float* emb    = (const float*)d_in[2];
    const float* wih    = (const float*)d_in[3];
    const float* whh    = (const float*)d_in[4];
    const float* bhh    = (const float*)d_in[5];
    float* out = (float*)d_out;

    char* ws = (char*)d_ws;
    const size_t o_whi = 0;
    const size_t o_wlo = o_whi + WHH_ELEMS*2;
    const size_t o_wih = o_wlo + WHH_ELEMS*2;   // wihp; reused as `part` during steps
    const size_t o_x   = o_wih + WIH_ELEMS*2;   // (WIH_ELEMS*2 == PART_ELEMS*4 == 9,216,000 B)
    const size_t o_gi  = o_x   + X_ELEMS*2;
    const size_t o_h16 = o_gi  + GI_ELEMS*2;
    const size_t o_h32 = o_h16 + 4*HB*2;
    const size_t need  = o_h32 + 2*HB*4;   // ~129 MB

    if (ws_size >= need) {
        f16* whip = (f16*)(ws + o_whi);
        f16* wlop = (f16*)(ws + o_wlo);
        f16* wihp = (f16*)(ws + o_wih);
        float* part = (float*)(ws + o_wih);     // overlays wihp (dead after gi GEMM)
        f16* xp   = (f16*)(ws + o_x);
        f16* gip  = (f16*)(ws + o_gi);
        f16* h16  = (f16*)(ws + o_h16);
        float* h32 = (float*)(ws + o_h32);
        f16* hhi[2]    = { h16,          h16 + 2*HB };
        f16* hlo[2]    = { h16 + HB,     h16 + 3*HB };
        float* h32b[2] = { h32, h32 + HB };

        hipMemsetAsync(ws + o_h16, 0, 4*HB*2 + 2*HB*4, stream);
        k_pack_whh<<<dim3(67500), dim3(256), 0, stream>>>(whh, whip, wlop);
        k_pack_wih<<<dim3(18000), dim3(256), 0, stream>>>(wih, wihp);
        k_gather_x<<<dim3(7680),  dim3(256), 0, stream>>>(tokens, emb, xp);
        k_gi_gemm<<<dim3(48,150), dim3(256), 0, stream>>>(xp, wihp, gip);
        for (int t=0; t<Tt; ++t){
            int c = t & 1, n = c ^ 1;
            k_gru_mfma<<<dim3(JT, KS), dim3(256), 0, stream>>>(
                hhi[c], hlo[c], whip, wlop, part);
            k_combine<<<dim3(600), dim3(256), 0, stream>>>(t, part, gip,
                h32b[c], h32b[n], hhi[n], hlo[n], bhh, lens, out);
        }
    } else {
        float* h32 = (float*)ws;
        float* hb[2] = { h32, h32 + HB };
        hipMemsetAsync(ws, 0, 2*HB*4, stream);
        for (int t=0; t<Tt; ++t){
            int c = t & 1, n = c ^ 1;
            k_fb_step<<<dim3(300), dim3(256), 0, stream>>>(t, hb[c], hb[n],
                tokens, lens, emb, wih, whh, bhh, out);
        }
    }
}